// Round 8
// baseline (797.454 us; speedup 1.0000x reference)
//
#include <hip/hip_runtime.h>
#include <stdint.h>
#include <stddef.h>

#define DEVFN __device__ __forceinline__

typedef float f32x4 __attribute__((ext_vector_type(4)));
typedef long i64_t;

constexpr int T_TOK = 4096, H_DIM = 2048, I_DIM = 1408;
constexpr int N_EXP = 8;
constexpr int P_PAIRS = T_TOK * 2;     // 8192 routed pairs
constexpr int BM = 64;                 // rows per tile
constexpr int MAXT = 144;              // >= sum ceil(cnt_e/64) <= 136
constexpr int GU_ROWS = 2 * I_DIM;     // 2816
constexpr int PP_PAD = P_PAIRS + 64;

// ---- workspace layout (bytes) ----
constexpr size_t OFF_WGU = 0;                                          // fp8 gup [E][2I][H]
constexpr size_t OFF_WD  = OFF_WGU + (size_t)N_EXP * GU_ROWS * H_DIM;  // fp8 down [E][H][I]
constexpr size_t OFF_XQ  = OFF_WD + (size_t)N_EXP * H_DIM * I_DIM;     // fp8 act quant [T][H]
constexpr size_t OFF_XS  = OFF_XQ + (size_t)T_TOK * H_DIM;             // f32 act scales [T][16]
constexpr size_t OFF_IQ  = OFF_XS + (size_t)T_TOK * 16 * 4;            // fp8 inter quant [P+64][I]
constexpr size_t OFF_IS  = OFF_IQ + (size_t)(P_PAIRS + BM) * I_DIM;    // f32 inter scales [11][P+64] k-major
constexpr size_t OFF_PS  = OFF_IS + (size_t)11 * PP_PAD * 4;           // pairs_sorted [P]
constexpr size_t OFF_PP  = OFF_PS + (size_t)P_PAIRS * 4;               // pos_of_pair [P]
constexpr size_t OFF_TE  = OFF_PP + (size_t)P_PAIRS * 4;               // tile expert
constexpr size_t OFF_TR  = OFF_TE + (size_t)MAXT * 4;                  // tile row start
constexpr size_t OFF_TM  = OFF_TR + (size_t)MAXT * 4;                  // tile rows
constexpr size_t OFF_Y   = (OFF_TM + (size_t)MAXT * 4 + 255) & ~(size_t)255;
constexpr size_t NEED_Y  = OFF_Y + (size_t)P_PAIRS * H_DIM * 4;        // y scratch [P][H] f32

// ---- exact RNE f32 -> OCP e4m3fn (input clamped to [-448,448], finite) ----
DEVFN unsigned f32_to_e4m3(float x) {
  unsigned u = __float_as_uint(x);
  unsigned s = (u >> 24) & 0x80u;
  int e = (int)((u >> 23) & 0xffu);
  unsigned m = u & 0x7fffffu;
  if (e == 0) return s;
  int ef = e - 127;
  if (ef < -10) return s;
  unsigned mant = 0x800000u | m;
  int shift = (ef < -6) ? (14 - ef) : 20;
  int e8 = (ef < -6) ? 0 : (ef + 7);
  unsigned keep = mant >> shift;
  unsigned rmask = 1u << (shift - 1);
  unsigned rbit = (mant & rmask) ? 1u : 0u;
  unsigned sticky = (mant & (rmask - 1u)) ? 1u : 0u;
  keep += (rbit & (sticky | (keep & 1u)));
  if (e8 == 0) {
    if (keep >= 8u) { e8 = 1; keep -= 8u; }
  } else {
    if (keep >= 16u) { keep >>= 1; e8 += 1; }
    keep -= 8u;
  }
  return s | ((unsigned)e8 << 3) | keep;
}

// ---- fast exact converter: input is EXACTLY an fp8 value stored in f32 ----
DEVFN unsigned e4x(float v) {
  unsigned u = __float_as_uint(v);
  unsigned s = (u >> 24) & 0x80u;
  unsigned au = u & 0x7fffffffu;
  if (au < 0x3c800000u)                       // |v| < 2^-6: fp8-subnormal/zero
    return s | (unsigned)(__uint_as_float(au) * 512.0f);
  return s | ((au - 0x3c000000u) >> 20);      // (E-120)<<3 | M>>20
}
DEVFN unsigned e4x4(float4 v) {
  return e4x(v.x) | (e4x(v.y) << 8) | (e4x(v.z) << 16) | (e4x(v.w) << 24);
}

DEVFN float clampq(float v) { return fminf(fmaxf(v, -448.f), 448.f); }

DEVFN void gll(const uint8_t* g, uint8_t* l) {
  __builtin_amdgcn_global_load_lds((const __attribute__((address_space(1))) void*)g,
                                   (__attribute__((address_space(3))) void*)l,
                                   16, 0, 0);
}

// ================= prep: weight cvt (both) + actq + route, one launch =================
constexpr int NB_WGU = 22528;                 // (8*2816*2048/8)/256
constexpr int NB_WD  = 11264;                 // (8*2048*1408/8)/256
constexpr int NB_W   = NB_WGU + NB_WD;        // 33792
constexpr int NB_PREP = NB_W + T_TOK + 1;     // 37889

__global__ __launch_bounds__(256) void k_prep(
    const float* __restrict__ gup_f, const float* __restrict__ dp_f,
    const float* __restrict__ x, const int* __restrict__ tki,
    uint8_t* __restrict__ wgu, uint8_t* __restrict__ wd,
    uint8_t* __restrict__ xq, float* __restrict__ xs,
    int* __restrict__ ps, int* __restrict__ pp,
    int* __restrict__ te, int* __restrict__ tr, int* __restrict__ tm) {
  __shared__ int cnt[8], off[9], cur[8];
  const int bx = blockIdx.x, tid = threadIdx.x;

  if (bx < NB_W) {                                        // weight convert, 8 f32/thread
    const float* src = (bx < NB_WGU) ? gup_f : dp_f;
    uint8_t* dst = (bx < NB_WGU) ? wgu : wd;
    size_t i = (size_t)(bx < NB_WGU ? bx : bx - NB_WGU) * 2048 + (size_t)tid * 8;
    float4 v0 = *(const float4*)(src + i);
    float4 v1 = *(const float4*)(src + i + 4);
    uint2 pk; pk.x = e4x4(v0); pk.y = e4x4(v1);
    *(uint2*)(dst + i) = pk;
    return;
  }
  if (bx < NB_W + T_TOK) {                                // activation quant
    int t = bx - NB_W;
    const float* row = x + (size_t)t * H_DIM + tid * 8;
    float4 v0 = *(const float4*)(row);
    float4 v1 = *(const float4*)(row + 4);
    float vals[8] = {v0.x, v0.y, v0.z, v0.w, v1.x, v1.y, v1.z, v1.w};
    float am = 0.f;
#pragma unroll
    for (int j = 0; j < 8; ++j) am = fmaxf(am, fabsf(vals[j]));
#pragma unroll
    for (int d = 1; d < 16; d <<= 1) am = fmaxf(am, __shfl_xor(am, d, 64));
    float s = fmaxf(am, 1e-12f) / 448.0f;
    if ((tid & 15) == 0) xs[(size_t)t * 16 + (tid >> 4)] = s;
    unsigned lo = 0, hi = 0;
#pragma unroll
    for (int j = 0; j < 4; ++j) lo |= f32_to_e4m3(clampq(vals[j] / s)) << (8 * j);
#pragma unroll
    for (int j = 0; j < 4; ++j) hi |= f32_to_e4m3(clampq(vals[4 + j] / s)) << (8 * j);
    uint2 pk; pk.x = lo; pk.y = hi;
    *(uint2*)(xq + (size_t)t * H_DIM + tid * 8) = pk;
    return;
  }
  // ---- routing (single block) ----
  if (tid < 8) cnt[tid] = 0;
  __syncthreads();
  for (int p = tid; p < P_PAIRS; p += 256) atomicAdd(&cnt[tki[p]], 1);
  __syncthreads();
  if (tid == 0) {
    int a = 0;
    for (int e = 0; e < 8; ++e) { off[e] = a; cur[e] = a; a += cnt[e]; }
    off[8] = a;
  }
  __syncthreads();
  for (int p = tid; p < P_PAIRS; p += 256) {
    int pos = atomicAdd(&cur[tki[p]], 1);
    ps[pos] = p;
    pp[p] = pos;
  }
  __syncthreads();
  if (tid == 0) {
    int nt = 0;
    for (int e = 0; e < 8; ++e)
      for (int s = off[e]; s < off[e + 1]; s += BM) {
        int rem = off[e + 1] - s;
        te[nt] = e; tr[nt] = s; tm[nt] = rem < BM ? rem : BM; ++nt;
      }
    for (; nt < MAXT; ++nt) { te[nt] = -1; tr[nt] = 0; tm[nt] = 0; }
  }
}

// ================= GEMM1: 2-phase double-buffered, BK=64, fused silu*up + quant =================
__global__ __launch_bounds__(256) void k_gemm1(
    const uint8_t* __restrict__ xq, const float* __restrict__ xs,
    const uint8_t* __restrict__ gup, const float* __restrict__ gsf,
    const int* __restrict__ te, const int* __restrict__ tr, const int* __restrict__ tm,
    const int* __restrict__ ps,
    uint8_t* __restrict__ iq, float* __restrict__ isv) {
  __shared__ uint8_t smA[2][64 * 64];       // 8 KB
  __shared__ uint8_t smBg[2][128 * 64];     // 16 KB
  __shared__ uint8_t smBu[2][128 * 64];     // 16 KB
  __shared__ __align__(16) float smSa[64];
  __shared__ float smRed[2][2][32];

  const int e = te[blockIdx.x];
  if (e < 0) return;
  const int r0 = tr[blockIdx.x], mrows = tm[blockIdx.x];
  const int nbg = blockIdx.y, n0 = nbg * 128;
  const int tid = threadIdx.x, lane = tid & 63, wid = tid >> 6;
  const int wm = wid >> 1, wn = wid & 1;
  const int lrow = lane & 15, lgrp = lane >> 4;
  const int mbase = wm * 32;

  // staging: thread -> (row_t = tid>>2, 16B col (tid&3)*16), source pre-swizzled
  const int row_t = tid >> 2;
  const int srcOff = ((tid & 3) * 16) ^ ((row_t & 3) << 4);
  const int tA = (row_t < mrows) ? (ps[r0 + row_t] >> 1) : 0;
  const uint8_t* gA   = xq + (size_t)tA * H_DIM + srcOff;
  const uint8_t* gBg  = gup + ((size_t)e * GU_ROWS + n0 + row_t) * H_DIM + srcOff;
  const uint8_t* gBg2 = gBg + (size_t)64 * H_DIM;
  const uint8_t* gBu  = gBg + (size_t)I_DIM * H_DIM;
  const uint8_t* gBu2 = gBu + (size_t)64 * H_DIM;
  uint8_t* lA  = smA[0]  + wid * 1024;   // wave-uniform base; HW appends lane*16
  uint8_t* lBg = smBg[0] + wid * 1024;
  uint8_t* lBu = smBu[0] + wid * 1024;

  int tS = 0;
  if (tid < 64) tS = (tid < mrows) ? (ps[r0 + tid] >> 1) : 0;
  const float* xsrow = xs + (size_t)tS * 16;

  // fragment LDS offsets (read-side swizzle matches source pre-swizzle)
  const int koff0 = (lgrp * 8) ^ ((lrow & 3) << 4);
  const int koff1 = koff0 ^ 32;
  const int rA0 = (mbase + lrow) * 64;
  const int rA1 = (mbase + 16 + lrow) * 64;
  int rB[4];
#pragma unroll
  for (int nf = 0; nf < 4; ++nf) rB[nf] = (wn * 64 + nf * 16 + lrow) * 64;

  const float* sfg = gsf + ((size_t)e * 22 + nbg) * 16;
  const float* sfu = gsf + ((size_t)e * 22 + 11 + nbg) * 16;

  f32x4 accg[2][4], accu[2][4], pg[2][4], pu[2][4];
#pragma unroll
  for (int mf = 0; mf < 2; ++mf)
#pragma unroll
    for (int nf = 0; nf < 4; ++nf) {
      accg[mf][nf] = 0.f; accu[mf][nf] = 0.f;
      pg[mf][nf] = 0.f;   pu[mf][nf] = 0.f;
    }

#define STAGE1(b_, s_) do { size_t o_ = (size_t)(s_) * 64;            \
    gll(gA + o_,   lA  + (b_) * 4096);                                \
    gll(gBg + o_,  lBg + (b_) * 8192);                                \
    gll(gBg2 + o_, lBg + (b_) * 8192 + 4096);                         \
    gll(gBu + o_,  lBu + (b_) * 8192);                                \
    gll(gBu2 + o_, lBu + (b_) * 8192 + 4096); } while (0)

  STAGE1(0, 0);
  if (tid < 64) smSa[tid] = xsrow[0];
  __syncthreads();                           // implicit vmcnt(0) drain

  for (int st = 0; st < 32; ++st) {
    const int buf = st & 1;
    if (st < 31) STAGE1(buf ^ 1, st + 1);    // issue next-tile loads EARLY
    if (st && !(st & 1) && tid < 64) smSa[tid] = xsrow[st >> 1];

    const uint8_t* bA = smA[0]  + buf * 4096;
    const uint8_t* bG = smBg[0] + buf * 8192;
    const uint8_t* bU = smBu[0] + buf * 8192;
    i64_t a00 = *(const i64_t*)(bA + rA0 + koff0);
    i64_t a01 = *(const i64_t*)(bA + rA0 + koff1);
    i64_t a10 = *(const i64_t*)(bA + rA1 + koff0);
    i64_t a11 = *(const i64_t*)(bA + rA1 + koff1);
#pragma unroll
    for (int nf = 0; nf < 4; ++nf) {
      i64_t bg0 = *(const i64_t*)(bG + rB[nf] + koff0);
      i64_t bg1 = *(const i64_t*)(bG + rB[nf] + koff1);
      i64_t bu0 = *(const i64_t*)(bU + rB[nf] + koff0);
      i64_t bu1 = *(const i64_t*)(bU + rB[nf] + koff1);
      pg[0][nf] = __builtin_amdgcn_mfma_f32_16x16x32_fp8_fp8(a00, bg0, pg[0][nf], 0, 0, 0);
      pg[0][nf] = __builtin_amdgcn_mfma_f32_16x16x32_fp8_fp8(a01, bg1, pg[0][nf], 0, 0, 0);
      pg[1][nf] = __builtin_amdgcn_mfma_f32_16x16x32_fp8_fp8(a10, bg0, pg[1][nf], 0, 0, 0);
      pg[1][nf] = __builtin_amdgcn_mfma_f32_16x16x32_fp8_fp8(a11, bg1, pg[1][nf], 0, 0, 0);
      pu[0][nf] = __builtin_amdgcn_mfma_f32_16x16x32_fp8_fp8(a00, bu0, pu[0][nf], 0, 0, 0);
      pu[0][nf] = __builtin_amdgcn_mfma_f32_16x16x32_fp8_fp8(a01, bu1, pu[0][nf], 0, 0, 0);
      pu[1][nf] = __builtin_amdgcn_mfma_f32_16x16x32_fp8_fp8(a10, bu0, pu[1][nf], 0, 0, 0);
      pu[1][nf] = __builtin_amdgcn_mfma_f32_16x16x32_fp8_fp8(a11, bu1, pu[1][nf], 0, 0, 0);
    }
    if (st & 1) {                            // end of a 128-K scale block
      const int kb = st >> 1;
      float swg = sfg[kb], swu = sfu[kb];
      f32x4 saf0 = *(const f32x4*)(smSa + mbase + lgrp * 4);
      f32x4 saf1 = *(const f32x4*)(smSa + mbase + 16 + lgrp * 4);
      f32x4 scg0 = saf0 * swg, scg1 = saf1 * swg;
      f32x4 scu0 = saf0 * swu, scu1 = saf1 * swu;
#pragma unroll
      for (int nf = 0; nf < 4; ++nf) {
        accg[0][nf] += pg[0][nf] * scg0; accg[1][nf] += pg[1][nf] * scg1;
        accu[0][nf] += pu[0][nf] * scu0; accu[1][nf] += pu[1][nf] * scu1;
        pg[0][nf] = 0.f; pg[1][nf] = 0.f; pu[0][nf] = 0.f; pu[1][nf] = 0.f;
      }
    }
    __syncthreads();                         // drain staged loads + ready next buf
  }
#undef STAGE1

  // ---- epilogue: inter = silu(g)*u, per-row amax over this 128-col block, fp8 quant ----
  float itv[2][4][4];
  float amx[2][4];
#pragma unroll
  for (int mf = 0; mf < 2; ++mf)
#pragma unroll
    for (int r = 0; r < 4; ++r) amx[mf][r] = 0.f;
#pragma unroll
  for (int mf = 0; mf < 2; ++mf)
#pragma unroll
    for (int nf = 0; nf < 4; ++nf)
#pragma unroll
      for (int r = 0; r < 4; ++r) {
        float g = accg[mf][nf][r], u = accu[mf][nf][r];
        float sg = 1.0f / (1.0f + expf(-g));
        float iv = g * sg * u;
        itv[mf][nf][r] = iv;
        amx[mf][r] = fmaxf(amx[mf][r], fabsf(iv));
      }
#pragma unroll
  for (int mf = 0; mf < 2; ++mf)
#pragma unroll
    for (int r = 0; r < 4; ++r)
#pragma unroll
      for (int d = 1; d < 16; d <<= 1) amx[mf][r] = fmaxf(amx[mf][r], __shfl_xor(amx[mf][r], d, 64));

  if (lrow == 0) {
#pragma unroll
    for (int mf = 0; mf < 2; ++mf)
#pragma unroll
      for (int r = 0; r < 4; ++r) smRed[wm][wn][mf * 16 + lgrp * 4 + r] = amx[mf][r];
  }
  __syncthreads();

#pragma unroll
  for (int mf = 0; mf < 2; ++mf)
#pragma unroll
    for (int r = 0; r < 4; ++r) {
      float am2 = fmaxf(amx[mf][r], smRed[wm][wn ^ 1][mf * 16 + lgrp * 4 + r]);
      float s = fmaxf(am2, 1e-12f) / 448.0f;
      int R = mbase + mf * 16 + lgrp * 4 + r;
      if (R < mrows) {
        if (wn == 0 && lrow == 0) isv[(size_t)nbg * PP_PAD + (r0 + R)] = s;
        size_t rowb = (size_t)(r0 + R) * I_DIM + n0 + wn * 64 + lrow;
#pragma unroll
        for (int nf = 0; nf < 4; ++nf) {
          float v = clampq(itv[mf][nf][r] / s);
          iq[rowb + nf * 16] = (uint8_t)f32_to_e4m3(v);
        }
      }
    }
}

// ================= GEMM2: 2-phase double-buffered, BK=64, weighted write =================
template <bool ATOMIC>
__global__ __launch_bounds__(256) void k_gemm2(
    const uint8_t* __restrict__ iq, const float* __restrict__ isv,
    const uint8_t* __restrict__ dp, const float* __restrict__ dsf,
    const int* __restrict__ te, const int* __restrict__ tr, const int* __restrict__ tm,
    const int* __restrict__ ps, const float* __restrict__ tkw,
    float* __restrict__ outy) {
  __shared__ uint8_t smA[2][64 * 64];       // 8 KB
  __shared__ uint8_t smB[2][128 * 64];      // 16 KB
  __shared__ __align__(16) float smSa[64];

  const int e = te[blockIdx.x];
  if (e < 0) return;
  const int r0 = tr[blockIdx.x], mrows = tm[blockIdx.x];
  const int nbg = blockIdx.y, n0 = nbg * 128;
  const int tid = threadIdx.x, lane = tid & 63, wid = tid >> 6;
  const int wm = wid >> 1, wn = wid & 1;
  const int lrow = lane & 15, lgrp = lane >> 4;
  const int mbase = wm * 32;

  const int row_t = tid >> 2;
  const int srcOff = ((tid & 3) * 16) ^ ((row_t & 3) << 4);
  const uint8_t* gA  = iq + (size_t)(r0 + row_t) * I_DIM + srcOff;   // iq padded +64 rows
  const uint8_t* gB  = dp + ((size_t)e * H_DIM + n0 + row_t) * I_DIM + srcOff;
  const uint8_t* gB2 = gB + (size_t)64 * I_DIM;
  uint8_t* lA = smA[0] + wid * 1024;
  uint8_t* lB = smB[0] + wid * 1024;

  const int koff0 = (lgrp * 8) ^ ((lrow & 3) << 4);
  const int koff1 = koff0 ^ 32;
  const int rA0 = (mbase + lrow) * 64;
  const int rA1 = (mbase + 16 + lrow) * 64;
  int rB[4];
#pragma unroll
  for (int nf = 0; nf < 4; ++nf) rB[nf] = (wn * 64 + nf * 16 + lrow) * 64;

  const float* sfd = dsf + ((size_t)e * 16 + nbg) * 11;

  f32x4 acc[2][4], p[2][4];
#pragma unroll
  for (int mf = 0; mf < 2; ++mf)
#pragma unroll
    for (int nf = 0; nf < 4; ++nf) { acc[mf][nf] = 0.f; p[mf][nf] = 0.f; }

#define STAGE2(b_, s_) do { size_t o_ = (size_t)(s_) * 64;            \
    gll(gA + o_,  lA + (b_) * 4096);                                  \
    gll(gB + o_,  lB + (b_) * 8192);                                  \
    gll(gB2 + o_, lB + (b_) * 8192 + 4096); } while (0)

  STAGE2(0, 0);
  if (tid < 64) smSa[tid] = isv[r0 + tid];   // kb=0 row-scales (k-major)
  __syncthreads();

  for (int st = 0; st < 22; ++st) {
    const int buf = st & 1;
    if (st < 21) STAGE2(buf ^ 1, st + 1);
    if (st && !(st & 1) && tid < 64) smSa[tid] = isv[(size_t)(st >> 1) * PP_PAD + r0 + tid];

    const uint8_t* bA = smA[0] + buf * 4096;
    const uint8_t* bB = smB[0] + buf * 8192;
    i64_t a00 = *(const i64_t*)(bA + rA0 + koff0);
    i64_t a01 = *(const i64_t*)(bA + rA0 + koff1);
    i64_t a10 = *(const i64_t*)(bA + rA1 + koff0);
    i64_t a11 = *(const i64_t*)(bA + rA1 + koff1);
#pragma unroll
    for (int nf = 0; nf < 4; ++nf) {
      i64_t b0 = *(const i64_t*)(bB + rB[nf] + koff0);
      i64_t b1 = *(const i64_t*)(bB + rB[nf] + koff1);
      p[0][nf] = __builtin_amdgcn_mfma_f32_16x16x32_fp8_fp8(a00, b0, p[0][nf], 0, 0, 0);
      p[0][nf] = __builtin_amdgcn_mfma_f32_16x16x32_fp8_fp8(a01, b1, p[0][nf], 0, 0, 0);
      p[1][nf] = __builtin_amdgcn_mfma_f32_16x16x32_fp8_fp8(a10, b0, p[1][nf], 0, 0, 0);
      p[1][nf] = __builtin_amdgcn_mfma_f32_16x16x32_fp8_fp8(a11, b1, p[1][nf], 0, 0, 0);
    }
    if (st & 1) {
      const int kb = st >> 1;
      float sw = sfd[kb];
      f32x4 saf0 = *(const f32x4*)(smSa + mbase + lgrp * 4);
      f32x4 saf1 = *(const f32x4*)(smSa + mbase + 16 + lgrp * 4);
      f32x4 sc0 = saf0 * sw, sc1 = saf1 * sw;
#pragma unroll
      for (int nf = 0; nf < 4; ++nf) {
        acc[0][nf] += p[0][nf] * sc0; acc[1][nf] += p[1][nf] * sc1;
        p[0][nf] = 0.f; p[1][nf] = 0.f;
      }
    }
    __syncthreads();
  }
#undef STAGE2

#pragma unroll
  for (int mf = 0; mf < 2; ++mf)
#pragma unroll
    for (int r = 0; r < 4; ++r) {
      int R = mbase + mf * 16 + lgrp * 4 + r;
      if (R < mrows) {
        int prow = r0 + R;
        int pidx = ps[prow];
        float w = tkw[pidx];
        if (ATOMIC) {
          float* ob = outy + (size_t)(pidx >> 1) * H_DIM + n0 + wn * 64 + lrow;
#pragma unroll
          for (int nf = 0; nf < 4; ++nf) atomicAdd(ob + nf * 16, acc[mf][nf][r] * w);
        } else {
          float* ob = outy + (size_t)prow * H_DIM + n0 + wn * 64 + lrow;
#pragma unroll
          for (int nf = 0; nf < 4; ++nf) ob[nf * 16] = acc[mf][nf][r] * w;
        }
      }
    }
}

// ================= combine =================
__global__ __launch_bounds__(256) void k_combine(const float* __restrict__ y,
                                                 const int* __restrict__ pp,
                                                 float* __restrict__ out) {
  size_t g = (size_t)blockIdx.x * 256 + threadIdx.x;
  int t = (int)(g >> 9);
  int c = (int)(g & 511) * 4;
  int ra = pp[2 * t], rb = pp[2 * t + 1];
  float4 va = *(const float4*)(y + (size_t)ra * H_DIM + c);
  float4 vb = *(const float4*)(y + (size_t)rb * H_DIM + c);
  float4 vo;
  vo.x = va.x + vb.x; vo.y = va.y + vb.y; vo.z = va.z + vb.z; vo.w = va.w + vb.w;
  *(float4*)(out + (size_t)t * H_DIM + c) = vo;
}

extern "C" void kernel_launch(void* const* d_in, const int* in_sizes, int n_in,
                              void* d_out, int out_size, void* d_ws, size_t ws_size,
                              hipStream_t stream) {
  (void)in_sizes; (void)n_in; (void)out_size;
  const float* x = (const float*)d_in[0];
  const int* tki = (const int*)d_in[1];
  const float* tkw = (const float*)d_in[2];
  const float* gup_f = (const float*)d_in[3];   // fp8 values delivered as f32
  const float* gsf = (const float*)d_in[4];
  const float* dp_f = (const float*)d_in[5];    // fp8 values delivered as f32
  const float* dsf = (const float*)d_in[6];
  float* out = (float*)d_out;
  uint8_t* ws = (uint8_t*)d_ws;

  uint8_t* wgu = ws + OFF_WGU;
  uint8_t* wd = ws + OFF_WD;
  uint8_t* xq = ws + OFF_XQ;
  float* xs = (float*)(ws + OFF_XS);
  uint8_t* iq = ws + OFF_IQ;
  float* isv = (float*)(ws + OFF_IS);
  int* ps = (int*)(ws + OFF_PS);
  int* pp = (int*)(ws + OFF_PP);
  int* te = (int*)(ws + OFF_TE);
  int* tr = (int*)(ws + OFF_TR);
  int* tm = (int*)(ws + OFF_TM);
  float* y = (float*)(ws + OFF_Y);

  k_prep<<<dim3(NB_PREP), dim3(256), 0, stream>>>(gup_f, dp_f, x, tki, wgu, wd,
                                                  xq, xs, ps, pp, te, tr, tm);
  k_gemm1<<<dim3(MAXT, 11), dim3(256), 0, stream>>>(xq, xs, wgu, gsf, te, tr, tm, ps, iq, isv);
  if (ws_size >= NEED_Y) {
    k_gemm2<false><<<dim3(MAXT, 16), dim3(256), 0, stream>>>(iq, isv, wd, dsf, te, tr, tm, ps, tkw, y);
    k_combine<<<dim3((T_TOK * (H_DIM / 4)) / 256), dim3(256), 0, stream>>>(y, pp, out);
  } else {
    hipMemsetAsync(d_out, 0, (size_t)T_TOK * H_DIM * sizeof(float), stream);
    k_gemm2<true><<<dim3(MAXT, 16), dim3(256), 0, stream>>>(iq, isv, wd, dsf, te, tr, tm, ps, tkw, out);
  }
}